// Round 3
// baseline (174.722 us; speedup 1.0000x reference)
//
#include <hip/hip_runtime.h>
#include <hip/hip_bf16.h>

typedef short short8 __attribute__((ext_vector_type(8)));   // 8 bf16 = 4 VGPRs
typedef float f32x4 __attribute__((ext_vector_type(4)));
typedef unsigned short u16;

__device__ __forceinline__ unsigned short f2bf(float f) {
  unsigned int u = __float_as_uint(f);
  u += 0x7fffu + ((u >> 16) & 1u);    // round-to-nearest-even
  return (unsigned short)(u >> 16);
}

// async 16B global->LDS (dest = wave-uniform base + lane*16)
__device__ __forceinline__ void glds16(const void* g, void* l) {
  __builtin_amdgcn_global_load_lds(
      (const __attribute__((address_space(1))) unsigned int*)g,
      (__attribute__((address_space(3))) unsigned int*)l, 16, 0, 0);
}

// Explicit full drain (vmcnt=0, expcnt=0, lgkmcnt=0) BEFORE s_barrier.
// __syncthreads alone is NOT a reliable fence for global_load_lds staging
// (r4-r7 flakiness; r8 passed with this).
__device__ __forceinline__ void drain_then_sync() {
  __builtin_amdgcn_s_waitcnt(0);
  __syncthreads();
}

// ---- fused: cast q/m -> bf16, cast wq*(1/(8 ln2)) -> bf16, cast wk, zero out ----
__global__ __launch_bounds__(256) void prep(const float4* __restrict__ q,
                                            const float4* __restrict__ m,
                                            const float4* __restrict__ wq,
                                            const float4* __restrict__ wk,
                                            ushort4* __restrict__ qb,
                                            ushort4* __restrict__ mb,
                                            ushort4* __restrict__ wqb,
                                            ushort4* __restrict__ wkb,
                                            float4* __restrict__ out0) {
  const int i = blockIdx.x * 256 + threadIdx.x;
  const float c = 0.18033688011112042f;  // 1/(8*ln2): folds SCALE and exp->exp2
  if (i < 1048576) {
    float4 v = q[i];
    ushort4 o; o.x = f2bf(v.x); o.y = f2bf(v.y); o.z = f2bf(v.z); o.w = f2bf(v.w);
    qb[i] = o;
  } else if (i < 2097152) {
    float4 v = m[i - 1048576];
    ushort4 o; o.x = f2bf(v.x); o.y = f2bf(v.y); o.z = f2bf(v.z); o.w = f2bf(v.w);
    mb[i - 1048576] = o;
  } else if (i < 2359296) {
    float4 v = wq[i - 2097152];
    ushort4 o; o.x = f2bf(v.x * c); o.y = f2bf(v.y * c); o.z = f2bf(v.z * c); o.w = f2bf(v.w * c);
    wqb[i - 2097152] = o;
  } else if (i < 2621440) {
    float4 v = wk[i - 2359296];
    ushort4 o; o.x = f2bf(v.x); o.y = f2bf(v.y); o.z = f2bf(v.z); o.w = f2bf(v.w);
    wkb[i - 2359296] = o;
  } else if (i < 2637824) {
    out0[i - 2621440] = (float4){0.f, 0.f, 0.f, 0.f};  // zero 65536-float output
  }
}

// ---- C = A[M,1024] @ B[N,1024]^T, 128x128 tile, BK=64, 512 thr (8 waves),
// double-buffered LDS, ONE drain+barrier per iter (r8-proven race-free).
__global__ __launch_bounds__(512) void gemm_db(const u16* __restrict__ A0,
                                               const u16* __restrict__ B0,
                                               u16* __restrict__ C0,
                                               const u16* __restrict__ A1,
                                               const u16* __restrict__ B1,
                                               u16* __restrict__ C1) {
  __shared__ u16 As[2][128 * 64];   // 32 KB
  __shared__ u16 Bs[2][128 * 64];   // 32 KB
  const int zz = blockIdx.x & 1;
  const u16* A = zz ? A1 : A0;
  const u16* B = zz ? B1 : B0;
  u16* C = zz ? C1 : C0;
  const int t = threadIdx.x;
  const int lane = t & 63, wave = t >> 6;     // 8 waves
  const int l15 = lane & 15, quad = lane >> 4;
  const int mb = (blockIdx.x >> 1) * 128;     // M-block (32 of them)
  const int nb = blockIdx.y * 128;            // N-block (8 of them)
  const int wm = (wave & 1) * 64;             // M: 2 x 64
  const int wn = (wave >> 1) * 32;            // N: 4 x 32

  const int srow = lane >> 3;                 // 0..7 row within 8-row group
  const int scol = ((lane & 7) ^ srow) * 8;   // xor-swizzled source column
  const int sw = l15 & 7;

  f32x4 acc[4][2];
#pragma unroll
  for (int i = 0; i < 4; i++)
#pragma unroll
    for (int j = 0; j < 2; j++) acc[i][j] = (f32x4){0.f, 0.f, 0.f, 0.f};

  // prologue: stage kb=0 into buffer 0 (2 A-groups + 2 B-groups per thread)
#pragma unroll
  for (int j = 0; j < 2; j++) {
    const int g = wave * 2 + j;               // 0..15 (8 rows each)
    glds16(A + (size_t)(mb + g * 8 + srow) * 1024 + scol, &As[0][g * 512 + lane * 8]);
    glds16(B + (size_t)(nb + g * 8 + srow) * 1024 + scol, &Bs[0][g * 512 + lane * 8]);
  }

  for (int it = 0; it < 16; ++it) {
    drain_then_sync();  // my buf[it] fills landed; all waves' buf[it^1] reads retired
    if (it < 15) {
      const int kb = (it + 1) * 64, bf_ = (it + 1) & 1;
#pragma unroll
      for (int j = 0; j < 2; j++) {
        const int g = wave * 2 + j;
        glds16(A + (size_t)(mb + g * 8 + srow) * 1024 + kb + scol, &As[bf_][g * 512 + lane * 8]);
        glds16(B + (size_t)(nb + g * 8 + srow) * 1024 + kb + scol, &Bs[bf_][g * 512 + lane * 8]);
      }
    }
    const u16* as = As[it & 1];
    const u16* bs = Bs[it & 1];
#pragma unroll
    for (int kk = 0; kk < 2; kk++) {
      const int cb = kk * 4;
      short8 af[4], bfr[2];
#pragma unroll
      for (int mi = 0; mi < 4; mi++)
        af[mi] = *(const short8*)&as[(wm + mi * 16 + l15) * 64 + ((cb + quad) ^ sw) * 8];
#pragma unroll
      for (int ni = 0; ni < 2; ni++)
        bfr[ni] = *(const short8*)&bs[(wn + ni * 16 + l15) * 64 + ((cb + quad) ^ sw) * 8];
#pragma unroll
      for (int mi = 0; mi < 4; mi++)
#pragma unroll
        for (int ni = 0; ni < 2; ni++)
          acc[mi][ni] = __builtin_amdgcn_mfma_f32_16x16x32_bf16(
              af[mi], bfr[ni], acc[mi][ni], 0, 0, 0);
    }
  }

  // epilogue: C/D layout col=l15, row=quad*4+r (r2-verified)
#pragma unroll
  for (int mi = 0; mi < 4; mi++)
#pragma unroll
    for (int r = 0; r < 4; r++) {
      const int row = mb + wm + mi * 16 + quad * 4 + r;
      const size_t base = (size_t)row * 1024 + nb + wn;
#pragma unroll
      for (int ni = 0; ni < 2; ni++)
        C[base + ni * 16 + l15] = f2bf(acc[mi][ni][r]);
    }
}

// ---- fused QK^T + columnwise LSE, NO LDS / NO barriers ----
// R2: drop Q LDS staging entirely (Common-mistake #7: Qp slab is L2/L3
// resident; the A-fragment global read pattern is IDENTICAL to the K-fragment
// loads that already work from global). Every wave is fully independent ->
// maximal phase mixing on the 1/8-rate trans pipe (the measured bottleneck:
// r8 VALUBusy 60% @ 50.3us vs ~27us exp-issue floor). LDS=0 + low VGPR
// restores the occupancy R1 destroyed (168 VGPR -> 10.5%). 2-tile software
// pipeline prefetches next alo/ahi during the exp burst (+8 VGPR only).
__global__ __launch_bounds__(256) void attn_lse2(const u16* __restrict__ Qp,
                                                 const u16* __restrict__ Kp,
                                                 float* __restrict__ out) {
  const int t = threadIdx.x;
  const int lane = t & 63, wave = t >> 6;    // 4 waves, fully independent
  const int l15 = lane & 15, quad = lane >> 4;
  const int kt = blockIdx.x & 1, aa = blockIdx.x >> 1;
  const int h = blockIdx.y, b = blockIdx.z;
  const int kwave = kt * 256 + wave * 64;

  // K fragments for 4 k-tiles x (d-lo, d-hi), in registers throughout
  short8 klo[4], khi[4];
#pragma unroll
  for (int tt = 0; tt < 4; tt++) {
    const short8* kg = (const short8*)(Kp + (size_t)(b * 512 + kwave + tt * 16 + l15) * 1024
                                       + h * 64 + quad * 8);
    klo[tt] = kg[0];
    khi[tt] = kg[4];   // +32 elements
  }

  // Q fragment base: row (qt*16 + l15), col h*64 + quad*8 (+32 for hi)
  const u16* qf = Qp + (size_t)(aa * 512 + l15) * 1024 + h * 64 + quad * 8;

  float cs0 = 0.f, cs1 = 0.f, cs2 = 0.f, cs3 = 0.f;

  // software pipeline: prefetch tile qt+1 during tile qt's exp burst
  short8 alo = *(const short8*)(qf);
  short8 ahi = *(const short8*)(qf + 32);

  for (int qt = 0; qt < 32; ++qt) {
    short8 nlo, nhi;
    if (qt < 31) {
      const u16* nf = qf + (size_t)(qt + 1) * 16 * 1024;
      nlo = *(const short8*)(nf);
      nhi = *(const short8*)(nf + 32);
    }
    f32x4 ac0 = (f32x4){0.f, 0.f, 0.f, 0.f};
    f32x4 ac1 = ac0, ac2 = ac0, ac3 = ac0;
    ac0 = __builtin_amdgcn_mfma_f32_16x16x32_bf16(alo, klo[0], ac0, 0, 0, 0);
    ac0 = __builtin_amdgcn_mfma_f32_16x16x32_bf16(ahi, khi[0], ac0, 0, 0, 0);
    ac1 = __builtin_amdgcn_mfma_f32_16x16x32_bf16(alo, klo[1], ac1, 0, 0, 0);
    ac1 = __builtin_amdgcn_mfma_f32_16x16x32_bf16(ahi, khi[1], ac1, 0, 0, 0);
    ac2 = __builtin_amdgcn_mfma_f32_16x16x32_bf16(alo, klo[2], ac2, 0, 0, 0);
    ac2 = __builtin_amdgcn_mfma_f32_16x16x32_bf16(ahi, khi[2], ac2, 0, 0, 0);
    ac3 = __builtin_amdgcn_mfma_f32_16x16x32_bf16(alo, klo[3], ac3, 0, 0, 0);
    ac3 = __builtin_amdgcn_mfma_f32_16x16x32_bf16(ahi, khi[3], ac3, 0, 0, 0);
#pragma unroll
    for (int r = 0; r < 4; r++) {
      cs0 += __builtin_amdgcn_exp2f(ac0[r]);   // bare v_exp_f32
      cs1 += __builtin_amdgcn_exp2f(ac1[r]);
      cs2 += __builtin_amdgcn_exp2f(ac2[r]);
      cs3 += __builtin_amdgcn_exp2f(ac3[r]);
    }
    alo = nlo; ahi = nhi;
  }
  // finish column sums over the 4 quads
  cs0 += __shfl_xor(cs0, 16); cs0 += __shfl_xor(cs0, 32);
  cs1 += __shfl_xor(cs1, 16); cs1 += __shfl_xor(cs1, 32);
  cs2 += __shfl_xor(cs2, 16); cs2 += __shfl_xor(cs2, 32);
  cs3 += __shfl_xor(cs3, 16); cs3 += __shfl_xor(cs3, 32);
  const float v = quad == 0 ? cs0 : quad == 1 ? cs1 : quad == 2 ? cs2 : cs3;
  atomicAdd(out + (size_t)b * 8192 + h * 512 + kwave + quad * 16 + l15, __logf(v));
}

extern "C" void kernel_launch(void* const* d_in, const int* in_sizes, int n_in,
                              void* d_out, int out_size, void* d_ws, size_t ws_size,
                              hipStream_t stream) {
  const float* query  = (const float*)d_in[0];  // [8,512,1024]
  const float* memory = (const float*)d_in[1];  // [8,512,1024]
  const float* wq     = (const float*)d_in[2];  // [1024,1024]
  const float* wk     = (const float*)d_in[3];  // [1024,1024]
  float* out = (float*)d_out;                   // [8,16,512]

  char* ws = (char*)d_ws;
  const size_t MB = 1024 * 1024;
  u16* qb  = (u16*)(ws);             // 8 MB bf16 query
  u16* mb_ = (u16*)(ws + 8  * MB);   // 8 MB bf16 memory
  u16* wqb = (u16*)(ws + 16 * MB);   // 2 MB bf16 W_Q * c
  u16* wkb = (u16*)(ws + 18 * MB);   // 2 MB bf16 W_K
  u16* Qp  = (u16*)(ws + 20 * MB);   // 8 MB projected Q'
  u16* Kp  = (u16*)(ws + 28 * MB);   // 8 MB projected K

  prep<<<10304, 256, 0, stream>>>((const float4*)query, (const float4*)memory,
                                  (const float4*)wq, (const float4*)wk,
                                  (ushort4*)qb, (ushort4*)mb_, (ushort4*)wqb,
                                  (ushort4*)wkb, (float4*)d_out);
  gemm_db<<<dim3(64, 8), 512, 0, stream>>>(qb, wqb, Qp, mb_, wkb, Kp);
  attn_lse2<<<dim3(16, 16, 8), 256, 0, stream>>>(Qp, Kp, out);
}

// Round 4
// 151.791 us; speedup vs baseline: 1.1511x; 1.1511x over previous
//
#include <hip/hip_runtime.h>
#include <hip/hip_bf16.h>

typedef short short8 __attribute__((ext_vector_type(8)));   // 8 bf16 = 4 VGPRs
typedef float f32x4 __attribute__((ext_vector_type(4)));
typedef unsigned short u16;

__device__ __forceinline__ unsigned short f2bf(float f) {
  unsigned int u = __float_as_uint(f);
  u += 0x7fffu + ((u >> 16) & 1u);    // round-to-nearest-even
  return (unsigned short)(u >> 16);
}

// async 16B global->LDS (dest = wave-uniform base + lane*16)
__device__ __forceinline__ void glds16(const void* g, void* l) {
  __builtin_amdgcn_global_load_lds(
      (const __attribute__((address_space(1))) unsigned int*)g,
      (__attribute__((address_space(3))) unsigned int*)l, 16, 0, 0);
}

// Explicit full drain (vmcnt=0, expcnt=0, lgkmcnt=0) BEFORE s_barrier.
// __syncthreads alone is NOT a reliable fence for global_load_lds staging
// (r4-r7 flakiness; r8 passed with this).
__device__ __forceinline__ void drain_then_sync() {
  __builtin_amdgcn_s_waitcnt(0);
  __syncthreads();
}

// ---- fused: cast q/m -> bf16, cast wq*(1/(8 ln2)) -> bf16, cast wk, zero out ----
__global__ __launch_bounds__(256) void prep(const float4* __restrict__ q,
                                            const float4* __restrict__ m,
                                            const float4* __restrict__ wq,
                                            const float4* __restrict__ wk,
                                            ushort4* __restrict__ qb,
                                            ushort4* __restrict__ mb,
                                            ushort4* __restrict__ wqb,
                                            ushort4* __restrict__ wkb,
                                            float4* __restrict__ out0) {
  const int i = blockIdx.x * 256 + threadIdx.x;
  const float c = 0.18033688011112042f;  // 1/(8*ln2): folds SCALE and exp->exp2
  if (i < 1048576) {
    float4 v = q[i];
    ushort4 o; o.x = f2bf(v.x); o.y = f2bf(v.y); o.z = f2bf(v.z); o.w = f2bf(v.w);
    qb[i] = o;
  } else if (i < 2097152) {
    float4 v = m[i - 1048576];
    ushort4 o; o.x = f2bf(v.x); o.y = f2bf(v.y); o.z = f2bf(v.z); o.w = f2bf(v.w);
    mb[i - 1048576] = o;
  } else if (i < 2359296) {
    float4 v = wq[i - 2097152];
    ushort4 o; o.x = f2bf(v.x * c); o.y = f2bf(v.y * c); o.z = f2bf(v.z * c); o.w = f2bf(v.w * c);
    wqb[i - 2097152] = o;
  } else if (i < 2621440) {
    float4 v = wk[i - 2359296];
    ushort4 o; o.x = f2bf(v.x); o.y = f2bf(v.y); o.z = f2bf(v.z); o.w = f2bf(v.w);
    wkb[i - 2359296] = o;
  } else if (i < 2637824) {
    out0[i - 2621440] = (float4){0.f, 0.f, 0.f, 0.f};  // zero 65536-float output
  }
}

// ---- C = A[M,1024] @ B[N,1024]^T, 128x128 tile, BK=64, 512 thr (8 waves),
// double-buffered LDS, ONE drain+barrier per iter (r8-proven race-free).
__global__ __launch_bounds__(512) void gemm_db(const u16* __restrict__ A0,
                                               const u16* __restrict__ B0,
                                               u16* __restrict__ C0,
                                               const u16* __restrict__ A1,
                                               const u16* __restrict__ B1,
                                               u16* __restrict__ C1) {
  __shared__ u16 As[2][128 * 64];   // 32 KB
  __shared__ u16 Bs[2][128 * 64];   // 32 KB
  const int zz = blockIdx.x & 1;
  const u16* A = zz ? A1 : A0;
  const u16* B = zz ? B1 : B0;
  u16* C = zz ? C1 : C0;
  const int t = threadIdx.x;
  const int lane = t & 63, wave = t >> 6;     // 8 waves
  const int l15 = lane & 15, quad = lane >> 4;
  const int mb = (blockIdx.x >> 1) * 128;     // M-block (32 of them)
  const int nb = blockIdx.y * 128;            // N-block (8 of them)
  const int wm = (wave & 1) * 64;             // M: 2 x 64
  const int wn = (wave >> 1) * 32;            // N: 4 x 32

  const int srow = lane >> 3;                 // 0..7 row within 8-row group
  const int scol = ((lane & 7) ^ srow) * 8;   // xor-swizzled source column
  const int sw = l15 & 7;

  f32x4 acc[4][2];
#pragma unroll
  for (int i = 0; i < 4; i++)
#pragma unroll
    for (int j = 0; j < 2; j++) acc[i][j] = (f32x4){0.f, 0.f, 0.f, 0.f};

  // prologue: stage kb=0 into buffer 0 (2 A-groups + 2 B-groups per thread)
#pragma unroll
  for (int j = 0; j < 2; j++) {
    const int g = wave * 2 + j;               // 0..15 (8 rows each)
    glds16(A + (size_t)(mb + g * 8 + srow) * 1024 + scol, &As[0][g * 512 + lane * 8]);
    glds16(B + (size_t)(nb + g * 8 + srow) * 1024 + scol, &Bs[0][g * 512 + lane * 8]);
  }

  for (int it = 0; it < 16; ++it) {
    drain_then_sync();  // my buf[it] fills landed; all waves' buf[it^1] reads retired
    if (it < 15) {
      const int kb = (it + 1) * 64, bf_ = (it + 1) & 1;
#pragma unroll
      for (int j = 0; j < 2; j++) {
        const int g = wave * 2 + j;
        glds16(A + (size_t)(mb + g * 8 + srow) * 1024 + kb + scol, &As[bf_][g * 512 + lane * 8]);
        glds16(B + (size_t)(nb + g * 8 + srow) * 1024 + kb + scol, &Bs[bf_][g * 512 + lane * 8]);
      }
    }
    const u16* as = As[it & 1];
    const u16* bs = Bs[it & 1];
#pragma unroll
    for (int kk = 0; kk < 2; kk++) {
      const int cb = kk * 4;
      short8 af[4], bfr[2];
#pragma unroll
      for (int mi = 0; mi < 4; mi++)
        af[mi] = *(const short8*)&as[(wm + mi * 16 + l15) * 64 + ((cb + quad) ^ sw) * 8];
#pragma unroll
      for (int ni = 0; ni < 2; ni++)
        bfr[ni] = *(const short8*)&bs[(wn + ni * 16 + l15) * 64 + ((cb + quad) ^ sw) * 8];
#pragma unroll
      for (int mi = 0; mi < 4; mi++)
#pragma unroll
        for (int ni = 0; ni < 2; ni++)
          acc[mi][ni] = __builtin_amdgcn_mfma_f32_16x16x32_bf16(
              af[mi], bfr[ni], acc[mi][ni], 0, 0, 0);
    }
  }

  // epilogue: C/D layout col=l15, row=quad*4+r (r2-verified)
#pragma unroll
  for (int mi = 0; mi < 4; mi++)
#pragma unroll
    for (int r = 0; r < 4; r++) {
      const int row = mb + wm + mi * 16 + quad * 4 + r;
      const size_t base = (size_t)row * 1024 + nb + wn;
#pragma unroll
      for (int ni = 0; ni < 2; ni++)
        C[base + ni * 16 + l15] = f2bf(acc[mi][ni][r]);
    }
}

// ---- fused QK^T + columnwise LSE: private per-wave LDS, ZERO barriers ----
// R4 synthesis of r1-r3 evidence:
//  - r8 (50.3us): coalesced glds16 staging good, but 8 workgroup-wide
//    drain+barriers phase-align waves -> trans pipe 55% utilized.
//  - R2 (78us): VGPR 168 killed occupancy. R3 no-LDS (81us): per-iteration
//    global-load latency serialized on the critical path (2450 cyc/iter).
// Fix: each wave double-buffers Q in its OWN 2x4KB LDS chunk. No cross-wave
// sharing -> NO s_barrier anywhere. Counted vmcnt(4) waits only for the
// PREVIOUS chunk's 4 fills; the next chunk's 4 stay in flight across the
// compute phase (2 qt-tiles ~ 512+ trans cycles >> L3 latency). Intra-wave
// ordering only -> race-free by construction. Waves drift into independent
// phases, filling the 1/8-rate trans pipe (the measured bottleneck).
__global__ __launch_bounds__(256) void attn_lse3(const u16* __restrict__ Qp,
                                                 const u16* __restrict__ Kp,
                                                 float* __restrict__ out) {
  __shared__ u16 qs[4][2][32 * 64];   // 4 waves x 2 bufs x 4KB = 32KB
  const int t = threadIdx.x;
  const int lane = t & 63, wave = t >> 6;    // 4 waves, fully independent
  const int l15 = lane & 15, quad = lane >> 4;
  const int kt = blockIdx.x & 1, aa = blockIdx.x >> 1;
  const int h = blockIdx.y, b = blockIdx.z;
  const int kwave = kt * 256 + wave * 64;

  // K fragments for 4 k-tiles x (d-lo, d-hi), in registers throughout
  short8 klo[4], khi[4];
#pragma unroll
  for (int tt = 0; tt < 4; tt++) {
    const short8* kg = (const short8*)(Kp + (size_t)(b * 512 + kwave + tt * 16 + l15) * 1024
                                       + h * 64 + quad * 8);
    klo[tt] = kg[0];
    khi[tt] = kg[4];   // +32 elements
  }

  const int srow = lane >> 3;                 // 0..7: row within 8-row group
  const int scol = ((lane & 7) ^ srow) * 8;   // xor-swizzled source column
  // per-thread staging source pointer, advanced 32 rows (64KB) per chunk
  const u16* qc = Qp + (size_t)(aa * 512 + srow) * 1024 + h * 64 + scol;

  // loop-invariant swizzled LDS read columns (in u16 elements)
  const int sw = l15 & 7;
  const int colLo = (quad ^ sw) * 8;
  const int colHi = ((4 + quad) ^ sw) * 8;
  const int rrow = l15 * 64;   // qt adds a compile-time 16*64 stride

  u16* const buf0 = &qs[wave][0][0];
  u16* const buf1 = &qs[wave][1][0];
  const int ldst = lane * 8;   // element offset of this lane's 16B slot

  // 16 independent add chains
  f32x4 csv0 = (f32x4){0.f, 0.f, 0.f, 0.f};
  f32x4 csv1 = csv0, csv2 = csv0, csv3 = csv0;

  // prologue: stage chunk 0 (32 q-rows) into buf0 -- 4 x 16B fills per lane
#pragma unroll
  for (int g = 0; g < 4; ++g)
    glds16(qc + (size_t)g * 8 * 1024, buf0 + g * 512 + ldst);

  for (int c = 0; c < 16; ++c) {
    const u16* cur = (c & 1) ? buf1 : buf0;
    u16* nxt = (c & 1) ? buf0 : buf1;
    if (c < 15) {
      const u16* qn = qc + (size_t)(c + 1) * 32 * 1024;
#pragma unroll
      for (int g = 0; g < 4; ++g)
        glds16(qn + (size_t)g * 8 * 1024, nxt + g * 512 + ldst);
      // wait for chunk c's 4 fills only; chunk c+1's 4 remain in flight
      asm volatile("s_waitcnt vmcnt(4)" ::: "memory");
    } else {
      asm volatile("s_waitcnt vmcnt(0)" ::: "memory");
    }
    __builtin_amdgcn_sched_barrier(0);   // rule #18: pin ds_reads after waitcnt
#pragma unroll
    for (int qt = 0; qt < 2; ++qt) {
      short8 alo = *(const short8*)&cur[qt * 1024 + rrow + colLo];
      short8 ahi = *(const short8*)&cur[qt * 1024 + rrow + colHi];
      f32x4 ac0 = (f32x4){0.f, 0.f, 0.f, 0.f};
      f32x4 ac1 = ac0, ac2 = ac0, ac3 = ac0;
      ac0 = __builtin_amdgcn_mfma_f32_16x16x32_bf16(alo, klo[0], ac0, 0, 0, 0);
      ac0 = __builtin_amdgcn_mfma_f32_16x16x32_bf16(ahi, khi[0], ac0, 0, 0, 0);
      ac1 = __builtin_amdgcn_mfma_f32_16x16x32_bf16(alo, klo[1], ac1, 0, 0, 0);
      ac1 = __builtin_amdgcn_mfma_f32_16x16x32_bf16(ahi, khi[1], ac1, 0, 0, 0);
      ac2 = __builtin_amdgcn_mfma_f32_16x16x32_bf16(alo, klo[2], ac2, 0, 0, 0);
      ac2 = __builtin_amdgcn_mfma_f32_16x16x32_bf16(ahi, khi[2], ac2, 0, 0, 0);
      ac3 = __builtin_amdgcn_mfma_f32_16x16x32_bf16(alo, klo[3], ac3, 0, 0, 0);
      ac3 = __builtin_amdgcn_mfma_f32_16x16x32_bf16(ahi, khi[3], ac3, 0, 0, 0);
#pragma unroll
      for (int r = 0; r < 4; r++) {
        csv0[r] += __builtin_amdgcn_exp2f(ac0[r]);   // bare v_exp_f32
        csv1[r] += __builtin_amdgcn_exp2f(ac1[r]);
        csv2[r] += __builtin_amdgcn_exp2f(ac2[r]);
        csv3[r] += __builtin_amdgcn_exp2f(ac3[r]);
      }
    }
  }
  // collapse vector chains, then finish column sums over the 4 quads
  float cs0 = csv0[0] + csv0[1] + csv0[2] + csv0[3];
  float cs1 = csv1[0] + csv1[1] + csv1[2] + csv1[3];
  float cs2 = csv2[0] + csv2[1] + csv2[2] + csv2[3];
  float cs3 = csv3[0] + csv3[1] + csv3[2] + csv3[3];
  cs0 += __shfl_xor(cs0, 16); cs0 += __shfl_xor(cs0, 32);
  cs1 += __shfl_xor(cs1, 16); cs1 += __shfl_xor(cs1, 32);
  cs2 += __shfl_xor(cs2, 16); cs2 += __shfl_xor(cs2, 32);
  cs3 += __shfl_xor(cs3, 16); cs3 += __shfl_xor(cs3, 32);
  const float v = quad == 0 ? cs0 : quad == 1 ? cs1 : quad == 2 ? cs2 : cs3;
  atomicAdd(out + (size_t)b * 8192 + h * 512 + kwave + quad * 16 + l15, __logf(v));
}

extern "C" void kernel_launch(void* const* d_in, const int* in_sizes, int n_in,
                              void* d_out, int out_size, void* d_ws, size_t ws_size,
                              hipStream_t stream) {
  const float* query  = (const float*)d_in[0];  // [8,512,1024]
  const float* memory = (const float*)d_in[1];  // [8,512,1024]
  const float* wq     = (const float*)d_in[2];  // [1024,1024]
  const float* wk     = (const float*)d_in[3];  // [1024,1024]
  float* out = (float*)d_out;                   // [8,16,512]

  char* ws = (char*)d_ws;
  const size_t MB = 1024 * 1024;
  u16* qb  = (u16*)(ws);             // 8 MB bf16 query
  u16* mb_ = (u16*)(ws + 8  * MB);   // 8 MB bf16 memory
  u16* wqb = (u16*)(ws + 16 * MB);   // 2 MB bf16 W_Q * c
  u16* wkb = (u16*)(ws + 18 * MB);   // 2 MB bf16 W_K
  u16* Qp  = (u16*)(ws + 20 * MB);   // 8 MB projected Q'
  u16* Kp  = (u16*)(ws + 28 * MB);   // 8 MB projected K

  prep<<<10304, 256, 0, stream>>>((const float4*)query, (const float4*)memory,
                                  (const float4*)wq, (const float4*)wk,
                                  (ushort4*)qb, (ushort4*)mb_, (ushort4*)wqb,
                                  (ushort4*)wkb, (float4*)d_out);
  gemm_db<<<dim3(64, 8), 512, 0, stream>>>(qb, wqb, Qp, mb_, wkb, Kp);
  attn_lse3<<<dim3(16, 16, 8), 256, 0, stream>>>(Qp, Kp, out);
}